// Round 1
// baseline (8519.040 us; speedup 1.0000x reference)
//
#include <hip/hip_runtime.h>
#include <hip/hip_bf16.h>
#include <math.h>

#define B 32
#define NN 4096
#define DK 128
#define HH 128
#define AA 128

// ws layout (in floats)
static const size_t OFF_ZF   = 0;                       // B*NN*AA = 16777216
static const size_t OFF_P    = OFF_ZF + (size_t)B*NN*AA; // B*NN
static const size_t OFF_COV  = OFF_P + (size_t)B*NN;     // B*NN
static const size_t OFF_S    = OFF_COV + (size_t)B*NN;   // 2*B
static const size_t OFF_CTX  = OFF_S + 2*B;              // 2*B*DK
static const size_t OFF_DECQ = OFF_CTX + (size_t)2*B*DK; // B*AA
static const size_t OFF_HST  = OFF_DECQ + (size_t)B*AA;  // B*HH
static const size_t OFF_CST  = OFF_HST + (size_t)B*HH;   // B*HH
static const size_t OFF_CNT  = OFF_CST + (size_t)B*HH;   // B ints

__device__ __forceinline__ float fast_tanh(float x) {
    float e = __expf(2.f * x);
    return 1.f - 2.f / (e + 1.f);
}
__device__ __forceinline__ float fast_sig(float x) {
    return 1.f / (1.f + __expf(-x));
}
__device__ __forceinline__ float agent_load(const float* p) {
    return __hip_atomic_load(p, __ATOMIC_RELAXED, __HIP_MEMORY_SCOPE_AGENT);
}

// ---- LSTM + dec_fea ("phase A") ----------------------------------------
// Computes h,c <- LSTMCell(s, (h,c)); decq[b,:] = [h,c]@W_x + b_attn.
// Requires >=256 threads participating (workers are tid<256); all threads of
// the block must call (contains __syncthreads).
__device__ void lstm_phase(int tid, int b, const float* __restrict__ sm_s,
                           float* hst, float* cst, float* decq,
                           const float* __restrict__ W_ih, const float* __restrict__ W_hh,
                           const float* __restrict__ b_ih, const float* __restrict__ b_hh,
                           const float* __restrict__ W_x, const float* __restrict__ b_attn)
{
    __shared__ float sm_h[HH];
    __shared__ float sm_g[4 * HH];
    __shared__ float sm_x[2 * HH];
    if (tid < HH) sm_h[tid] = hst[b * HH + tid];
    __syncthreads();
    if (tid < 256) {
        int j0 = tid, j1 = tid + 256;
        float g0 = b_ih[j0] + b_hh[j0];
        float g1 = b_ih[j1] + b_hh[j1];
        const float4* wi0 = (const float4*)(W_ih + (size_t)j0 * DK);
        const float4* wh0 = (const float4*)(W_hh + (size_t)j0 * HH);
        const float4* wi1 = (const float4*)(W_ih + (size_t)j1 * DK);
        const float4* wh1 = (const float4*)(W_hh + (size_t)j1 * HH);
        #pragma unroll 8
        for (int d4 = 0; d4 < DK / 4; ++d4) {
            float4 s4 = ((const float4*)sm_s)[d4];
            float4 h4 = ((const float4*)sm_h)[d4];
            float4 a0 = wi0[d4], a1 = wi1[d4];
            float4 c0 = wh0[d4], c1 = wh1[d4];
            g0 += s4.x*a0.x + s4.y*a0.y + s4.z*a0.z + s4.w*a0.w
                + h4.x*c0.x + h4.y*c0.y + h4.z*c0.z + h4.w*c0.w;
            g1 += s4.x*a1.x + s4.y*a1.y + s4.z*a1.z + s4.w*a1.w
                + h4.x*c1.x + h4.y*c1.y + h4.z*c1.z + h4.w*c1.w;
        }
        sm_g[j0] = g0; sm_g[j1] = g1;
    }
    __syncthreads();
    if (tid < HH) {
        float ig = sm_g[tid], fg = sm_g[HH + tid];
        float gg = sm_g[2 * HH + tid], og = sm_g[3 * HH + tid];
        float cold = cst[b * HH + tid];
        float cn = fast_sig(fg) * cold + fast_sig(ig) * fast_tanh(gg);
        float hn = fast_sig(og) * fast_tanh(cn);
        cst[b * HH + tid] = cn;
        hst[b * HH + tid] = hn;
        sm_x[tid] = hn;
        sm_x[HH + tid] = cn;
    }
    __syncthreads();
    if (tid < AA) {
        float df = b_attn[tid];
        #pragma unroll 8
        for (int k4 = 0; k4 < (2 * HH) / 4; ++k4) {
            float4 xv = ((const float4*)sm_x)[k4];
            df += xv.x * W_x[(size_t)(4 * k4 + 0) * AA + tid]
                + xv.y * W_x[(size_t)(4 * k4 + 1) * AA + tid]
                + xv.z * W_x[(size_t)(4 * k4 + 2) * AA + tid]
                + xv.w * W_x[(size_t)(4 * k4 + 3) * AA + tid];
        }
        decq[b * AA + tid] = df;
    }
    __syncthreads();
}

// ---- z_fea = z @ W_z ----------------------------------------------------
// 16 rows per block; Wz staged in LDS (64KB); thread (a, half) computes 8 rows.
__global__ __launch_bounds__(256) void zfea_kernel(const float* __restrict__ z,
                                                   const float* __restrict__ Wz,
                                                   float* __restrict__ zf)
{
    __shared__ float sWz[DK * AA];
    int tid = threadIdx.x;
    for (int i = tid; i < (DK * AA) / 4; i += 256)
        ((float4*)sWz)[i] = ((const float4*)Wz)[i];
    __syncthreads();

    int a = tid & 127;
    int half = tid >> 7;
    size_t r0 = (size_t)blockIdx.x * 16 + (size_t)half * 8;
    const float* zp = z + r0 * DK;
    float acc[8] = {0.f,0.f,0.f,0.f,0.f,0.f,0.f,0.f};
    for (int d4 = 0; d4 < 32; ++d4) {
        float w0 = sWz[(4 * d4 + 0) * AA + a];
        float w1 = sWz[(4 * d4 + 1) * AA + a];
        float w2 = sWz[(4 * d4 + 2) * AA + a];
        float w3 = sWz[(4 * d4 + 3) * AA + a];
        #pragma unroll
        for (int r = 0; r < 8; ++r) {
            float4 zv = *(const float4*)(zp + (size_t)r * DK + 4 * d4);
            acc[r] += zv.x * w0 + zv.y * w1 + zv.z * w2 + zv.w * w3;
        }
    }
    #pragma unroll
    for (int r = 0; r < 8; ++r)
        zf[(r0 + r) * AA + a] = acc[r];
}

// ---- prologue: zero state + initial LSTM (s=0, h0, c0) ------------------
__global__ __launch_bounds__(256) void prologue_kernel(
    const float* __restrict__ h0, const float* __restrict__ c0,
    float* cov, float* S, float* ctx, float* decq, float* hst, float* cst,
    int* cnt, float* out_closs,
    const float* __restrict__ W_ih, const float* __restrict__ W_hh,
    const float* __restrict__ b_ih, const float* __restrict__ b_hh,
    const float* __restrict__ W_x, const float* __restrict__ b_attn)
{
    int b = blockIdx.x;
    int tid = threadIdx.x;
    float4 zero4 = make_float4(0.f, 0.f, 0.f, 0.f);
    float4* c4 = (float4*)(cov + (size_t)b * NN);
    for (int i = tid; i < NN / 4; i += 256) c4[i] = zero4;
    if (tid < DK) ctx[b * DK + tid] = 0.f;  // ctx[buf 0]
    if (tid == 0) {
        S[b] = 0.f;
        cnt[b] = 0;
        if (b == 0) *out_closs = 0.f;
    }
    if (tid < HH) {
        hst[b * HH + tid] = h0[b * HH + tid];
        cst[b * HH + tid] = c0[b * HH + tid];
    }
    __shared__ float sm_s[DK];
    if (tid < DK) sm_s[tid] = 0.f;
    __syncthreads();
    lstm_phase(tid, b, sm_s, hst, cst, decq, W_ih, W_hh, b_ih, b_hh, W_x, b_attn);
}

// ---- one decode step ----------------------------------------------------
// grid 512 = 32 b * 16 chunks of 256 n; block 512 threads (8 waves, 32 n/wave)
__global__ __launch_bounds__(512) void step_kernel(
    const float* __restrict__ z, const float* __restrict__ mask,
    const float* __restrict__ w_c, const float* __restrict__ v,
    const float* __restrict__ zf, float* __restrict__ p, float* __restrict__ cov,
    float* S, float* ctx, float* decq, float* hst, float* cst, int* cnt,
    const float* __restrict__ W_ih, const float* __restrict__ W_hh,
    const float* __restrict__ b_ih, const float* __restrict__ b_hh,
    const float* __restrict__ W_x, const float* __restrict__ b_attn,
    float* __restrict__ out_text, float* __restrict__ out_attn, float* out_closs,
    int t, int T)
{
    const int tid = threadIdx.x;
    const int b = blockIdx.x & (B - 1);
    const int chunk = blockIdx.x >> 5;
    const int n0 = chunk * 256;
    const int cur = t & 1, prv = cur ^ 1;

    __shared__ float sm_cov[256];
    __shared__ float sm_p[256];
    __shared__ float sm_ctx[8][DK];
    __shared__ float sm_sump[8];
    __shared__ float sm_red[8];
    __shared__ int sm_done;

    float closs_part = 0.f;
    // --- B.1: finalize previous step's attention lazily (coalesced per n) ---
    if (tid < 256) {
        int n = n0 + tid;
        size_t bn = (size_t)b * NN + n;
        float covn = cov[bn];
        if (t > 0) {
            float invS = 1.f / S[prv * B + b];
            float ap = p[bn] * invS;
            out_attn[((size_t)b * T + (t - 1)) * NN + n] = ap;
            closs_part = fminf(ap, covn);
            covn += ap;
            cov[bn] = covn;
        }
        sm_cov[tid] = covn;
    }
    __syncthreads();

    // --- B.2: scores + exp + unnormalized context, one n per wave-iter ---
    const int w = tid >> 6, l = tid & 63;
    const float2* zf2 = (const float2*)(zf + ((size_t)b * NN + n0) * AA);
    const float2* z2  = (const float2*)(z  + ((size_t)b * NN + n0) * DK);
    const float2 q   = ((const float2*)(decq + b * AA))[l];   // dec_fea + b_attn
    const float2 wc2 = ((const float2*)w_c)[l];
    const float2 v2  = ((const float2*)v)[l];
    const float* mrow = mask + (size_t)b * NN + n0;
    float accx = 0.f, accy = 0.f;
    float sump = 0.f;
    for (int i = 0; i < 32; ++i) {
        const int nl = w * 32 + i;
        const float cvn = sm_cov[nl];
        const float2 a2 = zf2[(size_t)nl * 64 + l];
        float x0 = fmaf(cvn, wc2.x, a2.x + q.x);
        float x1 = fmaf(cvn, wc2.y, a2.y + q.y);
        float el = fast_tanh(x0) * v2.x + fast_tanh(x1) * v2.y;
        #pragma unroll
        for (int off = 32; off; off >>= 1) el += __shfl_xor(el, off, 64);
        float pe = (mrow[nl] > 0.f) ? __expf(el) : 0.f;
        if (l == 0) sm_p[nl] = pe;
        const float2 zr = z2[(size_t)nl * 64 + l];
        accx = fmaf(pe, zr.x, accx);
        accy = fmaf(pe, zr.y, accy);
        sump += pe;  // same value on all lanes; lane 0's copy is used
    }
    sm_ctx[w][2 * l]     = accx;
    sm_ctx[w][2 * l + 1] = accy;
    if (l == 0) sm_sump[w] = sump;
    #pragma unroll
    for (int off = 32; off; off >>= 1) closs_part += __shfl_xor(closs_part, off, 64);
    if (l == 0) sm_red[w] = closs_part;
    __syncthreads();

    // --- B.3: coalesced p store + block-level reduction into globals ---
    if (tid < 256) p[(size_t)b * NN + n0 + tid] = sm_p[tid];
    if (tid < DK) {
        float r = 0.f;
        #pragma unroll
        for (int ww = 0; ww < 8; ++ww) r += sm_ctx[ww][tid];
        atomicAdd(&ctx[(cur * B + b) * DK + tid], r);
    } else if (tid == DK) {
        float s8 = 0.f;
        #pragma unroll
        for (int ww = 0; ww < 8; ++ww) s8 += sm_sump[ww];
        atomicAdd(&S[cur * B + b], s8);
    } else if (tid == DK + 1 && t > 0) {
        float cl = 0.f;
        #pragma unroll
        for (int ww = 0; ww < 8; ++ww) cl += sm_red[ww];
        atomicAdd(out_closs, cl * (1.f / B));
    }
    __threadfence();
    __syncthreads();
    if (tid == 0) {
        int old = __hip_atomic_fetch_add(&cnt[b], 1, __ATOMIC_ACQ_REL, __HIP_MEMORY_SCOPE_AGENT);
        sm_done = (old == 15) ? 1 : 0;
    }
    __syncthreads();

    // --- last block for this b: normalize context, write text, next LSTM ---
    if (sm_done) {
        __shared__ float sm_s[DK];
        if (tid < DK) {
            float Sv = agent_load(&S[cur * B + b]);
            float cval = agent_load(&ctx[(cur * B + b) * DK + tid]);
            float ct = cval / Sv;
            out_text[((size_t)b * T + t) * DK + tid] = ct;
            sm_s[tid] = ct;
            ctx[(prv * B + b) * DK + tid] = 0.f;  // accumulator for step t+1
        }
        if (tid == 0) {
            S[prv * B + b] = 0.f;
            __hip_atomic_store(&cnt[b], 0, __ATOMIC_RELAXED, __HIP_MEMORY_SCOPE_AGENT);
        }
        __syncthreads();
        lstm_phase(tid, b, sm_s, hst, cst, decq, W_ih, W_hh, b_ih, b_hh, W_x, b_attn);
    }
}

// ---- epilogue: last step's attention + closs term -----------------------
__global__ __launch_bounds__(256) void epilogue_kernel(
    const float* __restrict__ p, const float* __restrict__ cov, const float* __restrict__ S,
    float* __restrict__ out_attn, float* out_closs, int T)
{
    const int tid = threadIdx.x;
    const int b = blockIdx.x & (B - 1);
    const int chunk = blockIdx.x >> 5;
    const int n = chunk * 256 + tid;
    const size_t bn = (size_t)b * NN + n;
    float invS = 1.f / S[((T - 1) & 1) * B + b];
    float ap = p[bn] * invS;
    out_attn[((size_t)b * T + (T - 1)) * NN + n] = ap;
    float cl = fminf(ap, cov[bn]);
    #pragma unroll
    for (int off = 32; off; off >>= 1) cl += __shfl_xor(cl, off, 64);
    __shared__ float sred[4];
    if ((tid & 63) == 0) sred[tid >> 6] = cl;
    __syncthreads();
    if (tid == 0)
        atomicAdd(out_closs, (sred[0] + sred[1] + sred[2] + sred[3]) * (1.f / B));
}

extern "C" void kernel_launch(void* const* d_in, const int* in_sizes, int n_in,
                              void* d_out, int out_size, void* d_ws, size_t ws_size,
                              hipStream_t stream) {
    const float* z      = (const float*)d_in[0];
    const float* mask   = (const float*)d_in[1];
    const float* h0     = (const float*)d_in[2];
    const float* c0     = (const float*)d_in[3];
    const float* W_ih   = (const float*)d_in[4];
    const float* W_hh   = (const float*)d_in[5];
    const float* b_ih   = (const float*)d_in[6];
    const float* b_hh   = (const float*)d_in[7];
    const float* W_x    = (const float*)d_in[8];
    const float* W_z    = (const float*)d_in[9];
    const float* w_c    = (const float*)d_in[10];
    const float* b_attn = (const float*)d_in[11];
    const float* v      = (const float*)d_in[12];

    int T = (out_size - 1) / (B * (NN + DK));
    if (T < 1) T = 1;

    float* ws   = (float*)d_ws;
    float* zf   = ws + OFF_ZF;
    float* p    = ws + OFF_P;
    float* cov  = ws + OFF_COV;
    float* S    = ws + OFF_S;
    float* ctx  = ws + OFF_CTX;
    float* decq = ws + OFF_DECQ;
    float* hst  = ws + OFF_HST;
    float* cst  = ws + OFF_CST;
    int*   cnt  = (int*)(ws + OFF_CNT);

    float* out_text  = (float*)d_out;
    float* out_attn  = out_text + (size_t)B * T * DK;
    float* out_closs = out_attn + (size_t)B * T * NN;

    zfea_kernel<<<(B * NN) / 16, 256, 0, stream>>>(z, W_z, zf);
    prologue_kernel<<<B, 256, 0, stream>>>(h0, c0, cov, S, ctx, decq, hst, cst,
                                           cnt, out_closs,
                                           W_ih, W_hh, b_ih, b_hh, W_x, b_attn);
    for (int t = 0; t < T; ++t) {
        step_kernel<<<512, 512, 0, stream>>>(z, mask, w_c, v, zf, p, cov, S, ctx,
                                             decq, hst, cst, cnt,
                                             W_ih, W_hh, b_ih, b_hh, W_x, b_attn,
                                             out_text, out_attn, out_closs, t, T);
    }
    epilogue_kernel<<<512, 256, 0, stream>>>(p, cov, S, out_attn, out_closs, T);
}